// Round 11
// baseline (183.052 us; speedup 1.0000x reference)
//
#include <hip/hip_runtime.h>
#include <hip/hip_fp16.h>
#include <stdint.h>
#include <string.h>

// LightGCN propagation — R25: R24 base (181.2us best-measured) + nontemporal
// hints on single-use streaming traffic (k1 barr stores, s1 barr loads,
// s1 ELL writeout) to stop L2 thrash of the xh gather table (s1 FETCH was
// 81MB vs 49MB mandatory => xh re-fetched ~3.4x).
//  K1: two-pass LDS-staged counting sort (320 buckets/pass, 36KB LDS,
//      2 blocks/CU) + parallel flat writeout (nt stores) + mark + cvt.
//  s1: per-bucket ELL build (nt barr loads) -> cnt-pruned writeout (nt)
//      -> layer-1 spmm from LDS; acc0 + mask expand + mask copy ride-alongs.
//  spmm2: global ELL (mask2 rows), fp16 gathers + acc1 ride-along.
//  sp3dot: slot-form layer 3 + fused batched dot (paired 16-lane groups).

#define NUM_USERS 100000
#define NUM_ITEMS 50000
#define N_NODES   150000
#define DIM       64
#define N_EDGES   1200000
#define ND        (N_NODES * DIM)
#define NB        4096
#define NSAMP     (2 * NB)

#define ELL_W     24
#define NBKT      640               // buckets
#define HB        320               // buckets staged per k1 pass
#define RPB       235               // rows per bucket (640*235 = 150400)
#define NROWS_PAD (NBKT * RPB)
#define BCAP      2176              // records per bucket array (mean 1875, +7s)
#define SCAP      13                // K1 LDS staging records per bucket
#define OVF_CAP   512

#define K1_THREADS     1024
#define K1_EDGE_BLOCKS 293          // 293*1024*4 = 1,200,128 >= N_EDGES
#define K1_MARK_BLOCKS 8            // 8*1024 = 8192 = NSAMP
#define K1_CVT_BLOCKS  208

#define S1_THREADS     512
#define S1_ACC_BLOCKS  256          // 32 slots/block * 256 = 8192
#define S1_EXP_BLOCKS  1024
#define S1_CPY_BLOCKS  293          // 293*512 >= N_NODES

#define SPMM_BLOCKS    9375         // 16 rows/block
#define ACC_BLOCKS     512          // 16 slots/block
#define SP3_BLOCKS     512          // 16 groups/block over 8192 slot-groups

// ---- fp16 pack/unpack helpers (compute in fp32) ---------------------------
__device__ __forceinline__ int h2i(__half2 h) { int r; memcpy(&r, &h, 4); return r; }
__device__ __forceinline__ __half2 i2h(int i) { __half2 h; memcpy(&h, &i, 4); return h; }

__device__ __forceinline__ float4 loadh4(const __half* p) {
    int2 v = *(const int2*)p;
    float2 a = __half22float2(i2h(v.x));
    float2 b = __half22float2(i2h(v.y));
    return make_float4(a.x, a.y, b.x, b.y);
}
__device__ __forceinline__ void storeh4(__half* p, float4 v) {
    int2 o;
    o.x = h2i(__floats2half2_rn(v.x, v.y));
    o.y = h2i(__floats2half2_rn(v.z, v.w));
    *(int2*)p = o;
}
__device__ __forceinline__ float4 f4fma(float v, float4 x, float4 a) {
    a.x += v * x.x; a.y += v * x.y; a.z += v * x.z; a.w += v * x.w;
    return a;
}

// nontemporal int2 store/load (streaming, no L2 allocate)
__device__ __forceinline__ void nt_store_i2(int2* p, int2 v) {
    __builtin_nontemporal_store(v.x, &p->x);
    __builtin_nontemporal_store(v.y, &p->y);
}
__device__ __forceinline__ int2 nt_load_i2(const int2* p) {
    int2 v;
    v.x = __builtin_nontemporal_load(&p->x);
    v.y = __builtin_nontemporal_load(&p->y);
    return v;
}
__device__ __forceinline__ void nt_store_i4(int4* p, int4 v) {
    __builtin_nontemporal_store(v.x, &p->x);
    __builtin_nontemporal_store(v.y, &p->y);
    __builtin_nontemporal_store(v.z, &p->z);
    __builtin_nontemporal_store(v.w, &p->w);
}

// ---------------------------------------------------------------------------
// K1: TWO-PASS LDS-staged counting sort (320 buckets/pass, 36KB LDS,
//     2 blocks/CU) + parallel flat writeout (nt) + mark + cvt ride-alongs
// ---------------------------------------------------------------------------
__global__ __launch_bounds__(K1_THREADS)
void k1_kernel(const int* __restrict__ erow,
               const int* __restrict__ ecol,
               const float* __restrict__ evalv,
               const int* __restrict__ users,
               const int* __restrict__ items,
               const float* __restrict__ ue,
               const float* __restrict__ ie,
               int* __restrict__ gtails,
               int2* __restrict__ barr,
               int4* __restrict__ ovf,
               int* __restrict__ ovf_cnt,
               unsigned char* __restrict__ mask3,
               __half* __restrict__ xh) {
    __shared__ int2 stage[HB * SCAP];     // 33.3 KB
    __shared__ int  scnt[HB];             // 1.25 KB
    __shared__ int  gpos[HB];             // 1.25 KB
    if (blockIdx.x < K1_EDGE_BLOCKS) {
        int base = ((int)blockIdx.x * K1_THREADS + (int)threadIdx.x) * 4;
        const bool have = base < N_EDGES;   // N_EDGES % 4 == 0 -> all 4 valid
        int4   r4 = {0,0,0,0};
        int4   c4 = {0,0,0,0};
        float4 v4 = {0,0,0,0};
        if (have) {
            r4 = *(const int4*)(erow + base);
            c4 = *(const int4*)(ecol + base);
            v4 = *(const float4*)(evalv + base);
        }
        int   rr[4] = {r4.x, r4.y, r4.z, r4.w};
        int   cc[4] = {c4.x, c4.y, c4.z, c4.w};
        float vv[4] = {v4.x, v4.y, v4.z, v4.w};
        for (int pass = 0; pass < 2; ++pass) {
            const int b0 = pass * HB;
            for (int k = threadIdx.x; k < HB; k += K1_THREADS) scnt[k] = 0;
            __syncthreads();
            if (have) {
                #pragma unroll
                for (int u = 0; u < 4; ++u) {
                    int b  = rr[u] / RPB;
                    int bl = b - b0;
                    if ((unsigned)bl >= (unsigned)HB) continue;  // other pass
                    int rloc = rr[u] - b * RPB;
                    int2 rec = make_int2(cc[u] | (rloc << 18), __float_as_int(vv[u]));
                    int s = atomicAdd(&scnt[bl], 1);
                    if (s < SCAP) {
                        stage[bl * SCAP + s] = rec;
                    } else {
                        // rare (~0.5%): spill straight to global
                        int gp = atomicAdd(&gtails[b], 1);
                        if (gp < BCAP) nt_store_i2(&barr[(size_t)b * BCAP + gp], rec);
                        else { int q = atomicAdd(ovf_cnt, 1);
                               if (q < OVF_CAP)
                                   ovf[q] = make_int4(rr[u], cc[u],
                                                      __float_as_int(vv[u]), 0); }
                    }
                }
            }
            __syncthreads();
            // grab per-bucket global ranges (one atomic per staged bucket)
            for (int bl = threadIdx.x; bl < HB; bl += K1_THREADS) {
                int c = scnt[bl];
                c = c < SCAP ? c : SCAP;   // clamp: spilled records already placed
                scnt[bl] = c;
                gpos[bl] = (c > 0) ? atomicAdd(&gtails[b0 + bl], c) : 0;
            }
            __syncthreads();
            // flat parallel writeout over (bucket, record) pairs
            for (int idx = threadIdx.x; idx < HB * SCAP; idx += K1_THREADS) {
                int bl = idx / SCAP;
                int i  = idx - bl * SCAP;
                if (i < scnt[bl]) {
                    int2 rc = stage[idx];
                    int gp = gpos[bl] + i;
                    int b  = b0 + bl;
                    if (gp < BCAP) nt_store_i2(&barr[(size_t)b * BCAP + gp], rc);
                    else { int q = atomicAdd(ovf_cnt, 1);
                           if (q < OVF_CAP)
                               ovf[q] = make_int4(b * RPB + (rc.x >> 18),
                                                  rc.x & 0x3FFFF, rc.y, 0); }
                }
            }
            __syncthreads();
        }
    } else if (blockIdx.x < K1_EDGE_BLOCKS + K1_MARK_BLOCKS) {
        int i = ((int)blockIdx.x - K1_EDGE_BLOCKS) * K1_THREADS + (int)threadIdx.x;
        if (i < NB)         mask3[users[i]] = 1;
        else if (i < NSAMP) mask3[NUM_USERS + items[i - NB]] = 1;
    } else {
        const int n4  = ND / 4;
        const int nu4 = NUM_USERS * DIM / 4;
        int i = ((int)blockIdx.x - K1_EDGE_BLOCKS - K1_MARK_BLOCKS) * K1_THREADS
                + (int)threadIdx.x;
        const int stride = K1_CVT_BLOCKS * K1_THREADS;
        int2* xh4 = (int2*)xh;
        for (; i < n4; i += stride) {
            float4 v = (i < nu4) ? ((const float4*)ue)[i]
                                 : ((const float4*)ie)[i - nu4];
            int2 o;
            o.x = h2i(__floats2half2_rn(v.x, v.y));
            o.y = h2i(__floats2half2_rn(v.z, v.w));
            xh4[i] = o;
        }
    }
}

// ---------------------------------------------------------------------------
// s1 (512 threads): ELL build (nt barr loads) + cnt-pruned writeout (nt)
//     + layer-1 spmm from LDS + acc0 + mask expand + mask copy ride-alongs
// ---------------------------------------------------------------------------
__global__ __launch_bounds__(S1_THREADS)
void s1_kernel(const int* __restrict__ erow,
               const int* __restrict__ ecol,
               const int* __restrict__ gtails,
               const int2* __restrict__ barr,
               const __half* __restrict__ xh,
               const float* __restrict__ ue,
               const float* __restrict__ ie,
               int* __restrict__ counts,
               int2* __restrict__ ell,
               int4* __restrict__ ovf,
               int* __restrict__ ovf_cnt,
               const unsigned char* __restrict__ mask3,
               unsigned char* __restrict__ mask2,
               const int* __restrict__ users,
               const int* __restrict__ items,
               float* __restrict__ acc_small,
               __half* __restrict__ emb_out) {
    __shared__ __align__(16) int2 lell[RPB * ELL_W];   // 45.1 KB
    __shared__ int lcnt[RPB];
    const int group = threadIdx.x >> 4;   // 0..31
    const int t     = threadIdx.x & 15;

    if (blockIdx.x < NBKT) {
        const int bkt   = blockIdx.x;
        const int rbase = bkt * RPB;
        // ---- phase 1: build LDS ELL from sorted records (nt loads) ----
        for (int k = threadIdx.x; k < RPB; k += S1_THREADS) lcnt[k] = 0;
        __syncthreads();
        int n = gtails[bkt];
        n = n < BCAP ? n : BCAP;
        for (int e = threadIdx.x; e < n; e += S1_THREADS) {
            int2 rec = nt_load_i2(&barr[(size_t)bkt * BCAP + e]);
            int col  = rec.x & 0x3FFFF;
            int rloc = rec.x >> 18;
            int slot = atomicAdd(&lcnt[rloc], 1);
            if (slot < ELL_W)
                lell[rloc * ELL_W + slot] = make_int2(col, rec.y);
            else { int q = atomicAdd(ovf_cnt, 1);
                   if (q < OVF_CAP) ovf[q] = make_int4(rbase + rloc, col, rec.y, 0); }
        }
        __syncthreads();
        // ---- phase 2: cnt-pruned writeout, nt (rows are 192B line-aligned) ----
        {
            int4* g4 = (int4*)(ell + (size_t)rbase * ELL_W);
            const int4* l4 = (const int4*)lell;
            const int PPR = ELL_W / 2;   // 12 int4 pairs per row
            for (int idx = threadIdx.x; idx < RPB * PPR; idx += S1_THREADS) {
                int row = idx / PPR;
                int pr  = idx - row * PPR;
                int c = lcnt[row]; c = c < ELL_W ? c : ELL_W;
                if (pr * 2 < c) nt_store_i4(&g4[idx], l4[idx]);
            }
            for (int k = threadIdx.x; k < RPB; k += S1_THREADS)
                counts[rbase + k] = lcnt[k];
        }
        // ---- phase 3: layer-1 spmm reading ELL from LDS ----
        int novf = *ovf_cnt;
        novf = novf < OVF_CAP ? novf : OVF_CAP;
        for (int k = 0; k < 8; ++k) {                 // 32 groups x 8 = 256 >= 235
            int rloc = group + 32 * k;
            if (rloc >= RPB) break;
            int row = rbase + rloc;
            if (row >= N_NODES) continue;
            int cnt = lcnt[rloc];
            cnt = cnt < ELL_W ? cnt : ELL_W;
            const int2* ep = &lell[rloc * ELL_W];
            float4 a0 = {0,0,0,0}, a1 = {0,0,0,0}, a2 = {0,0,0,0}, a3 = {0,0,0,0};
            int j = 0;
            for (; j + 4 <= cnt; j += 4) {
                int4 cv0 = *(const int4*)(ep + j);
                int4 cv1 = *(const int4*)(ep + j + 2);
                float4 x0 = loadh4(xh + (size_t)cv0.x * DIM + t * 4);
                float4 x1 = loadh4(xh + (size_t)cv0.z * DIM + t * 4);
                float4 x2 = loadh4(xh + (size_t)cv1.x * DIM + t * 4);
                float4 x3 = loadh4(xh + (size_t)cv1.z * DIM + t * 4);
                a0 = f4fma(__int_as_float(cv0.y), x0, a0);
                a1 = f4fma(__int_as_float(cv0.w), x1, a1);
                a2 = f4fma(__int_as_float(cv1.y), x2, a2);
                a3 = f4fma(__int_as_float(cv1.w), x3, a3);
            }
            for (; j + 2 <= cnt; j += 2) {
                int4 cv = *(const int4*)(ep + j);
                float4 x0 = loadh4(xh + (size_t)cv.x * DIM + t * 4);
                float4 x1 = loadh4(xh + (size_t)cv.z * DIM + t * 4);
                a0 = f4fma(__int_as_float(cv.y), x0, a0);
                a1 = f4fma(__int_as_float(cv.w), x1, a1);
            }
            if (j < cnt) {
                int2 cv = ep[j];
                float4 xv = loadh4(xh + (size_t)cv.x * DIM + t * 4);
                a0 = f4fma(__int_as_float(cv.y), xv, a0);
            }
            for (int q = 0; q < novf; ++q) {
                int4 o = ovf[q];
                if (o.x == row) {
                    float4 xv = loadh4(xh + (size_t)o.y * DIM + t * 4);
                    a0 = f4fma(__int_as_float(o.z), xv, a0);
                }
            }
            float4 self = loadh4(xh + (size_t)row * DIM + t * 4);
            float4 r;
            r.x = 0.2f * self.x + 0.8f * ((a0.x + a1.x) + (a2.x + a3.x));
            r.y = 0.2f * self.y + 0.8f * ((a0.y + a1.y) + (a2.y + a3.y));
            r.z = 0.2f * self.z + 0.8f * ((a0.z + a1.z) + (a2.z + a3.z));
            r.w = 0.2f * self.w + 0.8f * ((a0.w + a1.w) + (a2.w + a3.w));
            storeh4(emb_out + (size_t)row * DIM + t * 4, r);
        }
    } else if (blockIdx.x < NBKT + S1_ACC_BLOCKS) {
        // acc0: store layer-0 contribution from the fp32 tables (32 slots/blk)
        const int s = ((int)blockIdx.x - NBKT) * 32 + group;   // < 8192
        const int node = (s < NB) ? users[s] : (NUM_USERS + items[s - NB]);
        const float* p = (node < NUM_USERS) ? ue + (size_t)node * DIM
                                            : ie + (size_t)(node - NUM_USERS) * DIM;
        *(float4*)(acc_small + (size_t)s * DIM + t * 4) = *(const float4*)(p + t * 4);
    } else if (blockIdx.x < NBKT + S1_ACC_BLOCKS + S1_EXP_BLOCKS) {
        int i = ((int)blockIdx.x - NBKT - S1_ACC_BLOCKS) * S1_THREADS
                + (int)threadIdx.x;
        const int stride = S1_EXP_BLOCKS * S1_THREADS;
        for (; i < N_EDGES; i += stride)
            if (mask3[erow[i]]) mask2[ecol[i]] = 1;
    } else {
        int i = ((int)blockIdx.x - NBKT - S1_ACC_BLOCKS - S1_EXP_BLOCKS) * S1_THREADS
                + (int)threadIdx.x;
        if (i < N_NODES && mask3[i]) mask2[i] = 1;
    }
}

// ---------------------------------------------------------------------------
// spmm2 (layer 2): global ELL, masked, fp16 gathers + acc1 ride-along
// ---------------------------------------------------------------------------
__global__ void spmm_kernel(const int* __restrict__ counts,
                            const int2* __restrict__ ell,
                            const __half* __restrict__ xsrc,
                            const unsigned char* __restrict__ mask,
                            const int* __restrict__ ovf_cnt,
                            const int4* __restrict__ ovf,
                            const int* __restrict__ users,
                            const int* __restrict__ items,
                            float* __restrict__ acc_small,
                            __half* __restrict__ xout) {
    const int wid  = threadIdx.x >> 6;
    const int lane = threadIdx.x & 63;
    const int g    = lane >> 4;
    const int t    = lane & 15;

    if (blockIdx.x < SPMM_BLOCKS) {
        const int row = blockIdx.x * 16 + wid * 4 + g;
        bool active = mask[row] != 0;
        int cnt = 0;
        if (active) {
            cnt = counts[row];
            cnt = cnt < ELL_W ? cnt : ELL_W;
        }
        const int2* ep = ell + (size_t)row * ELL_W;
        float4 a0 = {0,0,0,0}, a1 = {0,0,0,0}, a2 = {0,0,0,0}, a3 = {0,0,0,0};
        int j = 0;
        for (; j + 4 <= cnt; j += 4) {
            int4 cv0 = *(const int4*)(ep + j);
            int4 cv1 = *(const int4*)(ep + j + 2);
            float4 x0 = loadh4(xsrc + (size_t)cv0.x * DIM + t * 4);
            float4 x1 = loadh4(xsrc + (size_t)cv0.z * DIM + t * 4);
            float4 x2 = loadh4(xsrc + (size_t)cv1.x * DIM + t * 4);
            float4 x3 = loadh4(xsrc + (size_t)cv1.z * DIM + t * 4);
            a0 = f4fma(__int_as_float(cv0.y), x0, a0);
            a1 = f4fma(__int_as_float(cv0.w), x1, a1);
            a2 = f4fma(__int_as_float(cv1.y), x2, a2);
            a3 = f4fma(__int_as_float(cv1.w), x3, a3);
        }
        for (; j + 2 <= cnt; j += 2) {
            int4 cv = *(const int4*)(ep + j);
            float4 x0 = loadh4(xsrc + (size_t)cv.x * DIM + t * 4);
            float4 x1 = loadh4(xsrc + (size_t)cv.z * DIM + t * 4);
            a0 = f4fma(__int_as_float(cv.y), x0, a0);
            a1 = f4fma(__int_as_float(cv.w), x1, a1);
        }
        if (j < cnt) {
            int2 cv = ep[j];
            float4 xv = loadh4(xsrc + (size_t)cv.x * DIM + t * 4);
            a0 = f4fma(__int_as_float(cv.y), xv, a0);
        }
        int novf = *ovf_cnt;
        if (novf > 0) {
            novf = novf < OVF_CAP ? novf : OVF_CAP;
            for (int k = 0; k < novf; ++k) {
                int4 o = ovf[k];
                if (active && o.x == row) {
                    float4 xv = loadh4(xsrc + (size_t)o.y * DIM + t * 4);
                    a0 = f4fma(__int_as_float(o.z), xv, a0);
                }
            }
        }
        if (active) {
            float4 self = loadh4(xsrc + (size_t)row * DIM + t * 4);
            float4 r;
            r.x = 0.2f * self.x + 0.8f * ((a0.x + a1.x) + (a2.x + a3.x));
            r.y = 0.2f * self.y + 0.8f * ((a0.y + a1.y) + (a2.y + a3.y));
            r.z = 0.2f * self.z + 0.8f * ((a0.z + a1.z) + (a2.z + a3.z));
            r.w = 0.2f * self.w + 0.8f * ((a0.w + a1.w) + (a2.w + a3.w));
            storeh4(xout + (size_t)row * DIM + t * 4, r);
        }
    } else {
        // acc1 += e1 at sampled slots (xsrc = emb_a)
        const int s = (blockIdx.x - SPMM_BLOCKS) * 16 + wid * 4 + g;
        const int node = (s < NB) ? users[s] : (NUM_USERS + items[s - NB]);
        float4 v = loadh4(xsrc + (size_t)node * DIM + t * 4);
        float4* ap = (float4*)(acc_small + (size_t)s * DIM + t * 4);
        float4 a = *ap;
        a.x += v.x; a.y += v.y; a.z += v.z; a.w += v.w;
        *ap = a;
    }
}

// ---------------------------------------------------------------------------
// sp3dot: slot-form layer 3 + fused batched dot.
//   Pair (user slot w, item slot NB+w) sit in adjacent 16-lane groups of the
//   same wave -> partner acc via shfl_xor(16), reduce via shfl_xor(1,2,4,8).
// ---------------------------------------------------------------------------
__global__ void sp3dot_kernel(const int* __restrict__ counts,
                              const int2* __restrict__ ell,
                              const __half* __restrict__ emb2,
                              const int* __restrict__ ovf_cnt,
                              const int4* __restrict__ ovf,
                              const int* __restrict__ users,
                              const int* __restrict__ items,
                              const float* __restrict__ acc_small,
                              float* __restrict__ out) {
    const int wid  = threadIdx.x >> 6;
    const int lane = threadIdx.x & 63;
    const int g    = lane >> 4;
    const int t    = lane & 15;
    const int G    = blockIdx.x * 16 + wid * 4 + g;       // < 8192
    if (G >= NSAMP) return;
    const int w    = G >> 1;
    const int role = G & 1;                    // 0 = user slot, 1 = item slot
    const int s    = role ? (NB + w) : w;
    const int node = role ? (NUM_USERS + items[w]) : users[w];

    int cnt = counts[node];
    cnt = cnt < ELL_W ? cnt : ELL_W;
    const int2* ep = ell + (size_t)node * ELL_W;
    float4 a0 = {0,0,0,0}, a1 = {0,0,0,0}, a2 = {0,0,0,0}, a3 = {0,0,0,0};
    int j = 0;
    for (; j + 4 <= cnt; j += 4) {
        int4 cv0 = *(const int4*)(ep + j);
        int4 cv1 = *(const int4*)(ep + j + 2);
        float4 x0 = loadh4(emb2 + (size_t)cv0.x * DIM + t * 4);
        float4 x1 = loadh4(emb2 + (size_t)cv0.z * DIM + t * 4);
        float4 x2 = loadh4(emb2 + (size_t)cv1.x * DIM + t * 4);
        float4 x3 = loadh4(emb2 + (size_t)cv1.z * DIM + t * 4);
        a0 = f4fma(__int_as_float(cv0.y), x0, a0);
        a1 = f4fma(__int_as_float(cv0.w), x1, a1);
        a2 = f4fma(__int_as_float(cv1.y), x2, a2);
        a3 = f4fma(__int_as_float(cv1.w), x3, a3);
    }
    for (; j + 2 <= cnt; j += 2) {
        int4 cv = *(const int4*)(ep + j);
        float4 x0 = loadh4(emb2 + (size_t)cv.x * DIM + t * 4);
        float4 x1 = loadh4(emb2 + (size_t)cv.z * DIM + t * 4);
        a0 = f4fma(__int_as_float(cv.y), x0, a0);
        a1 = f4fma(__int_as_float(cv.w), x1, a1);
    }
    if (j < cnt) {
        int2 cv = ep[j];
        float4 xv = loadh4(emb2 + (size_t)cv.x * DIM + t * 4);
        a0 = f4fma(__int_as_float(cv.y), xv, a0);
    }
    int novf = *ovf_cnt;
    if (novf > 0) {
        novf = novf < OVF_CAP ? novf : OVF_CAP;
        for (int k = 0; k < novf; ++k) {
            int4 o = ovf[k];
            if (o.x == node) {
                float4 xv = loadh4(emb2 + (size_t)o.y * DIM + t * 4);
                a0 = f4fma(__int_as_float(o.z), xv, a0);
            }
        }
    }
    float4 self = loadh4(emb2 + (size_t)node * DIM + t * 4);
    float4 a = *(const float4*)(acc_small + (size_t)s * DIM + t * 4);  // e0+e1
    a.x += 1.2f * self.x + 0.8f * ((a0.x + a1.x) + (a2.x + a3.x));
    a.y += 1.2f * self.y + 0.8f * ((a0.y + a1.y) + (a2.y + a3.y));
    a.z += 1.2f * self.z + 0.8f * ((a0.z + a1.z) + (a2.z + a3.z));
    a.w += 1.2f * self.w + 0.8f * ((a0.w + a1.w) + (a2.w + a3.w));
    // fused dot: partner group is lane^16 within the same wave
    float4 b;
    b.x = __shfl_xor(a.x, 16, 64);
    b.y = __shfl_xor(a.y, 16, 64);
    b.z = __shfl_xor(a.z, 16, 64);
    b.w = __shfl_xor(a.w, 16, 64);
    float p = a.x * b.x + a.y * b.y + a.z * b.z + a.w * b.w;
    p += __shfl_xor(p, 1, 64);
    p += __shfl_xor(p, 2, 64);
    p += __shfl_xor(p, 4, 64);
    p += __shfl_xor(p, 8, 64);
    if (role == 0 && t == 0) out[w] = p * 0.0625f;   // (u/4)·(i/4)
}

// ---------------------------------------------------------------------------
extern "C" void kernel_launch(void* const* d_in, const int* in_sizes, int n_in,
                              void* d_out, int out_size, void* d_ws, size_t ws_size,
                              hipStream_t stream) {
    const int*   users = (const int*)  d_in[0];
    const int*   items = (const int*)  d_in[1];
    const int*   erow  = (const int*)  d_in[2];
    const int*   ecol  = (const int*)  d_in[3];
    const float* evalv = (const float*)d_in[4];
    const float* ue    = (const float*)d_in[5];
    const float* ie    = (const float*)d_in[6];
    float* out = (float*)d_out;

    // workspace layout (~101 MB)
    __half* xh        = (__half*)d_ws;                      // 19.2 MB
    __half* emb_a     = xh + ND;                            // 19.2 MB
    __half* emb_b     = emb_a + ND;                         // 19.2 MB
    float*  acc_small = (float*)(emb_b + ND);               // 2 MB
    int2*   barr      = (int2*)(acc_small + NSAMP * DIM);   // 11.1 MB
    int2*   ell       = barr + (size_t)NBKT * BCAP;         // 28.9 MB
    int*    counts    = (int*)(ell + (size_t)NROWS_PAD * ELL_W); // 0.6 MB
    int*    gtails    = counts + NROWS_PAD;                 // NBKT
    int*    ovf_cnt   = gtails + NBKT;                      // 1
    int4*   ovf       = (int4*)(((uintptr_t)(ovf_cnt + 1) + 15) & ~(uintptr_t)15);
    unsigned char* mask3 = (unsigned char*)(ovf + OVF_CAP); // N_NODES
    unsigned char* mask2 = mask3 + N_NODES;                 // N_NODES

    // zero gtails | ovf_cnt | ovf | mask3 | mask2 (contiguous, ~310 KB)
    size_t zbytes = (size_t)((mask2 + N_NODES) - (unsigned char*)gtails);
    hipMemsetAsync(gtails, 0, zbytes, stream);

    k1_kernel<<<K1_EDGE_BLOCKS + K1_MARK_BLOCKS + K1_CVT_BLOCKS, K1_THREADS, 0, stream>>>(
        erow, ecol, evalv, users, items, ue, ie,
        gtails, barr, ovf, ovf_cnt, mask3, xh);

    // s1: ELL build + pruned writeout + layer-1 spmm + acc0 + expand + copy
    s1_kernel<<<NBKT + S1_ACC_BLOCKS + S1_EXP_BLOCKS + S1_CPY_BLOCKS, S1_THREADS, 0, stream>>>(
        erow, ecol, gtails, barr, xh, ue, ie, counts, ell, ovf, ovf_cnt,
        mask3, mask2, users, items, acc_small, emb_a);

    // layer 2 (mask2) + acc1 (from emb_a)
    spmm_kernel<<<SPMM_BLOCKS + ACC_BLOCKS, 256, 0, stream>>>(
        counts, ell, emb_a, mask2, ovf_cnt, ovf,
        users, items, acc_small, emb_b);

    // layer 3 slot-form + fused dot
    sp3dot_kernel<<<SP3_BLOCKS, 256, 0, stream>>>(
        counts, ell, emb_b, ovf_cnt, ovf, users, items, acc_small, out);
}

// Round 12
// 179.775 us; speedup vs baseline: 1.0182x; 1.0182x over previous
//
#include <hip/hip_runtime.h>
#include <hip/hip_fp16.h>
#include <stdint.h>
#include <string.h>

// LightGCN propagation — R26: revert R25's nontemporal hints (null result:
// s1's excess FETCH is mandatory gather re-fetch of a 19MB working set vs
// 4MB L2, not pollution). This is R24 verbatim — the best-measured config
// (181.2us). Session ledger:
//  - s1 gather: latency-floor, occupancy-insensitive (R21, R23 null)
//  - k1 sort: two-pass staging (R24 win, +2x occupancy)
//  - spmm2 packing: net-neutral (R19/R20/R22)
//  - mega-fusion / global-atomic ELL / global counters: regressions (R16/18/19)
//  K1: two-pass LDS-staged counting sort (320 buckets/pass, 36KB LDS,
//      2 blocks/CU) + parallel flat writeout + mark + cvt ride-alongs.
//  s1: per-bucket ELL build (LDS) -> cnt-pruned writeout -> layer-1 spmm
//      from LDS; acc0 + mask expand + mask copy ride-alongs.
//  spmm2: global ELL (mask2 rows), fp16 gathers + acc1 ride-along.
//  sp3dot: slot-form layer 3 + fused batched dot (paired 16-lane groups).

#define NUM_USERS 100000
#define NUM_ITEMS 50000
#define N_NODES   150000
#define DIM       64
#define N_EDGES   1200000
#define ND        (N_NODES * DIM)
#define NB        4096
#define NSAMP     (2 * NB)

#define ELL_W     24
#define NBKT      640               // buckets
#define HB        320               // buckets staged per k1 pass
#define RPB       235               // rows per bucket (640*235 = 150400)
#define NROWS_PAD (NBKT * RPB)
#define BCAP      2176              // records per bucket array (mean 1875, +7s)
#define SCAP      13                // K1 LDS staging records per bucket
#define OVF_CAP   512

#define K1_THREADS     1024
#define K1_EDGE_BLOCKS 293          // 293*1024*4 = 1,200,128 >= N_EDGES
#define K1_MARK_BLOCKS 8            // 8*1024 = 8192 = NSAMP
#define K1_CVT_BLOCKS  208

#define S1_THREADS     512
#define S1_ACC_BLOCKS  256          // 32 slots/block * 256 = 8192
#define S1_EXP_BLOCKS  1024
#define S1_CPY_BLOCKS  293          // 293*512 >= N_NODES

#define SPMM_BLOCKS    9375         // 16 rows/block
#define ACC_BLOCKS     512          // 16 slots/block
#define SP3_BLOCKS     512          // 16 groups/block over 8192 slot-groups

// ---- fp16 pack/unpack helpers (compute in fp32) ---------------------------
__device__ __forceinline__ int h2i(__half2 h) { int r; memcpy(&r, &h, 4); return r; }
__device__ __forceinline__ __half2 i2h(int i) { __half2 h; memcpy(&h, &i, 4); return h; }

__device__ __forceinline__ float4 loadh4(const __half* p) {
    int2 v = *(const int2*)p;
    float2 a = __half22float2(i2h(v.x));
    float2 b = __half22float2(i2h(v.y));
    return make_float4(a.x, a.y, b.x, b.y);
}
__device__ __forceinline__ void storeh4(__half* p, float4 v) {
    int2 o;
    o.x = h2i(__floats2half2_rn(v.x, v.y));
    o.y = h2i(__floats2half2_rn(v.z, v.w));
    *(int2*)p = o;
}
__device__ __forceinline__ float4 f4fma(float v, float4 x, float4 a) {
    a.x += v * x.x; a.y += v * x.y; a.z += v * x.z; a.w += v * x.w;
    return a;
}

// ---------------------------------------------------------------------------
// K1: TWO-PASS LDS-staged counting sort (320 buckets/pass, 36KB LDS,
//     2 blocks/CU) + parallel flat writeout + mark + cvt ride-alongs
// ---------------------------------------------------------------------------
__global__ __launch_bounds__(K1_THREADS)
void k1_kernel(const int* __restrict__ erow,
               const int* __restrict__ ecol,
               const float* __restrict__ evalv,
               const int* __restrict__ users,
               const int* __restrict__ items,
               const float* __restrict__ ue,
               const float* __restrict__ ie,
               int* __restrict__ gtails,
               int2* __restrict__ barr,
               int4* __restrict__ ovf,
               int* __restrict__ ovf_cnt,
               unsigned char* __restrict__ mask3,
               __half* __restrict__ xh) {
    __shared__ int2 stage[HB * SCAP];     // 33.3 KB
    __shared__ int  scnt[HB];             // 1.25 KB
    __shared__ int  gpos[HB];             // 1.25 KB
    if (blockIdx.x < K1_EDGE_BLOCKS) {
        int base = ((int)blockIdx.x * K1_THREADS + (int)threadIdx.x) * 4;
        const bool have = base < N_EDGES;   // N_EDGES % 4 == 0 -> all 4 valid
        int4   r4 = {0,0,0,0};
        int4   c4 = {0,0,0,0};
        float4 v4 = {0,0,0,0};
        if (have) {
            r4 = *(const int4*)(erow + base);
            c4 = *(const int4*)(ecol + base);
            v4 = *(const float4*)(evalv + base);
        }
        int   rr[4] = {r4.x, r4.y, r4.z, r4.w};
        int   cc[4] = {c4.x, c4.y, c4.z, c4.w};
        float vv[4] = {v4.x, v4.y, v4.z, v4.w};
        for (int pass = 0; pass < 2; ++pass) {
            const int b0 = pass * HB;
            for (int k = threadIdx.x; k < HB; k += K1_THREADS) scnt[k] = 0;
            __syncthreads();
            if (have) {
                #pragma unroll
                for (int u = 0; u < 4; ++u) {
                    int b  = rr[u] / RPB;
                    int bl = b - b0;
                    if ((unsigned)bl >= (unsigned)HB) continue;  // other pass
                    int rloc = rr[u] - b * RPB;
                    int2 rec = make_int2(cc[u] | (rloc << 18), __float_as_int(vv[u]));
                    int s = atomicAdd(&scnt[bl], 1);
                    if (s < SCAP) {
                        stage[bl * SCAP + s] = rec;
                    } else {
                        // rare (~0.5%): spill straight to global
                        int gp = atomicAdd(&gtails[b], 1);
                        if (gp < BCAP) barr[(size_t)b * BCAP + gp] = rec;
                        else { int q = atomicAdd(ovf_cnt, 1);
                               if (q < OVF_CAP)
                                   ovf[q] = make_int4(rr[u], cc[u],
                                                      __float_as_int(vv[u]), 0); }
                    }
                }
            }
            __syncthreads();
            // grab per-bucket global ranges (one atomic per staged bucket)
            for (int bl = threadIdx.x; bl < HB; bl += K1_THREADS) {
                int c = scnt[bl];
                c = c < SCAP ? c : SCAP;   // clamp: spilled records already placed
                scnt[bl] = c;
                gpos[bl] = (c > 0) ? atomicAdd(&gtails[b0 + bl], c) : 0;
            }
            __syncthreads();
            // flat parallel writeout over (bucket, record) pairs
            for (int idx = threadIdx.x; idx < HB * SCAP; idx += K1_THREADS) {
                int bl = idx / SCAP;
                int i  = idx - bl * SCAP;
                if (i < scnt[bl]) {
                    int2 rc = stage[idx];
                    int gp = gpos[bl] + i;
                    int b  = b0 + bl;
                    if (gp < BCAP) barr[(size_t)b * BCAP + gp] = rc;
                    else { int q = atomicAdd(ovf_cnt, 1);
                           if (q < OVF_CAP)
                               ovf[q] = make_int4(b * RPB + (rc.x >> 18),
                                                  rc.x & 0x3FFFF, rc.y, 0); }
                }
            }
            __syncthreads();
        }
    } else if (blockIdx.x < K1_EDGE_BLOCKS + K1_MARK_BLOCKS) {
        int i = ((int)blockIdx.x - K1_EDGE_BLOCKS) * K1_THREADS + (int)threadIdx.x;
        if (i < NB)         mask3[users[i]] = 1;
        else if (i < NSAMP) mask3[NUM_USERS + items[i - NB]] = 1;
    } else {
        const int n4  = ND / 4;
        const int nu4 = NUM_USERS * DIM / 4;
        int i = ((int)blockIdx.x - K1_EDGE_BLOCKS - K1_MARK_BLOCKS) * K1_THREADS
                + (int)threadIdx.x;
        const int stride = K1_CVT_BLOCKS * K1_THREADS;
        int2* xh4 = (int2*)xh;
        for (; i < n4; i += stride) {
            float4 v = (i < nu4) ? ((const float4*)ue)[i]
                                 : ((const float4*)ie)[i - nu4];
            int2 o;
            o.x = h2i(__floats2half2_rn(v.x, v.y));
            o.y = h2i(__floats2half2_rn(v.z, v.w));
            xh4[i] = o;
        }
    }
}

// ---------------------------------------------------------------------------
// s1 (512 threads): ELL build (LDS) + cnt-pruned writeout + layer-1 spmm
//     from LDS + acc0 + mask expand + mask copy ride-alongs
// ---------------------------------------------------------------------------
__global__ __launch_bounds__(S1_THREADS)
void s1_kernel(const int* __restrict__ erow,
               const int* __restrict__ ecol,
               const int* __restrict__ gtails,
               const int2* __restrict__ barr,
               const __half* __restrict__ xh,
               const float* __restrict__ ue,
               const float* __restrict__ ie,
               int* __restrict__ counts,
               int2* __restrict__ ell,
               int4* __restrict__ ovf,
               int* __restrict__ ovf_cnt,
               const unsigned char* __restrict__ mask3,
               unsigned char* __restrict__ mask2,
               const int* __restrict__ users,
               const int* __restrict__ items,
               float* __restrict__ acc_small,
               __half* __restrict__ emb_out) {
    __shared__ __align__(16) int2 lell[RPB * ELL_W];   // 45.1 KB
    __shared__ int lcnt[RPB];
    const int group = threadIdx.x >> 4;   // 0..31
    const int t     = threadIdx.x & 15;

    if (blockIdx.x < NBKT) {
        const int bkt   = blockIdx.x;
        const int rbase = bkt * RPB;
        // ---- phase 1: build LDS ELL from sorted records ----
        for (int k = threadIdx.x; k < RPB; k += S1_THREADS) lcnt[k] = 0;
        __syncthreads();
        int n = gtails[bkt];
        n = n < BCAP ? n : BCAP;
        for (int e = threadIdx.x; e < n; e += S1_THREADS) {
            int2 rec = barr[(size_t)bkt * BCAP + e];
            int col  = rec.x & 0x3FFFF;
            int rloc = rec.x >> 18;
            int slot = atomicAdd(&lcnt[rloc], 1);
            if (slot < ELL_W)
                lell[rloc * ELL_W + slot] = make_int2(col, rec.y);
            else { int q = atomicAdd(ovf_cnt, 1);
                   if (q < OVF_CAP) ovf[q] = make_int4(rbase + rloc, col, rec.y, 0); }
        }
        __syncthreads();
        // ---- phase 2: cnt-pruned writeout (rows are 192B line-aligned) ----
        {
            int4* g4 = (int4*)(ell + (size_t)rbase * ELL_W);
            const int4* l4 = (const int4*)lell;
            const int PPR = ELL_W / 2;   // 12 int4 pairs per row
            for (int idx = threadIdx.x; idx < RPB * PPR; idx += S1_THREADS) {
                int row = idx / PPR;
                int pr  = idx - row * PPR;
                int c = lcnt[row]; c = c < ELL_W ? c : ELL_W;
                if (pr * 2 < c) g4[idx] = l4[idx];
            }
            for (int k = threadIdx.x; k < RPB; k += S1_THREADS)
                counts[rbase + k] = lcnt[k];
        }
        // ---- phase 3: layer-1 spmm reading ELL from LDS ----
        int novf = *ovf_cnt;
        novf = novf < OVF_CAP ? novf : OVF_CAP;
        for (int k = 0; k < 8; ++k) {                 // 32 groups x 8 = 256 >= 235
            int rloc = group + 32 * k;
            if (rloc >= RPB) break;
            int row = rbase + rloc;
            if (row >= N_NODES) continue;
            int cnt = lcnt[rloc];
            cnt = cnt < ELL_W ? cnt : ELL_W;
            const int2* ep = &lell[rloc * ELL_W];
            float4 a0 = {0,0,0,0}, a1 = {0,0,0,0}, a2 = {0,0,0,0}, a3 = {0,0,0,0};
            int j = 0;
            for (; j + 4 <= cnt; j += 4) {
                int4 cv0 = *(const int4*)(ep + j);
                int4 cv1 = *(const int4*)(ep + j + 2);
                float4 x0 = loadh4(xh + (size_t)cv0.x * DIM + t * 4);
                float4 x1 = loadh4(xh + (size_t)cv0.z * DIM + t * 4);
                float4 x2 = loadh4(xh + (size_t)cv1.x * DIM + t * 4);
                float4 x3 = loadh4(xh + (size_t)cv1.z * DIM + t * 4);
                a0 = f4fma(__int_as_float(cv0.y), x0, a0);
                a1 = f4fma(__int_as_float(cv0.w), x1, a1);
                a2 = f4fma(__int_as_float(cv1.y), x2, a2);
                a3 = f4fma(__int_as_float(cv1.w), x3, a3);
            }
            for (; j + 2 <= cnt; j += 2) {
                int4 cv = *(const int4*)(ep + j);
                float4 x0 = loadh4(xh + (size_t)cv.x * DIM + t * 4);
                float4 x1 = loadh4(xh + (size_t)cv.z * DIM + t * 4);
                a0 = f4fma(__int_as_float(cv.y), x0, a0);
                a1 = f4fma(__int_as_float(cv.w), x1, a1);
            }
            if (j < cnt) {
                int2 cv = ep[j];
                float4 xv = loadh4(xh + (size_t)cv.x * DIM + t * 4);
                a0 = f4fma(__int_as_float(cv.y), xv, a0);
            }
            for (int q = 0; q < novf; ++q) {
                int4 o = ovf[q];
                if (o.x == row) {
                    float4 xv = loadh4(xh + (size_t)o.y * DIM + t * 4);
                    a0 = f4fma(__int_as_float(o.z), xv, a0);
                }
            }
            float4 self = loadh4(xh + (size_t)row * DIM + t * 4);
            float4 r;
            r.x = 0.2f * self.x + 0.8f * ((a0.x + a1.x) + (a2.x + a3.x));
            r.y = 0.2f * self.y + 0.8f * ((a0.y + a1.y) + (a2.y + a3.y));
            r.z = 0.2f * self.z + 0.8f * ((a0.z + a1.z) + (a2.z + a3.z));
            r.w = 0.2f * self.w + 0.8f * ((a0.w + a1.w) + (a2.w + a3.w));
            storeh4(emb_out + (size_t)row * DIM + t * 4, r);
        }
    } else if (blockIdx.x < NBKT + S1_ACC_BLOCKS) {
        // acc0: store layer-0 contribution from the fp32 tables (32 slots/blk)
        const int s = ((int)blockIdx.x - NBKT) * 32 + group;   // < 8192
        const int node = (s < NB) ? users[s] : (NUM_USERS + items[s - NB]);
        const float* p = (node < NUM_USERS) ? ue + (size_t)node * DIM
                                            : ie + (size_t)(node - NUM_USERS) * DIM;
        *(float4*)(acc_small + (size_t)s * DIM + t * 4) = *(const float4*)(p + t * 4);
    } else if (blockIdx.x < NBKT + S1_ACC_BLOCKS + S1_EXP_BLOCKS) {
        int i = ((int)blockIdx.x - NBKT - S1_ACC_BLOCKS) * S1_THREADS
                + (int)threadIdx.x;
        const int stride = S1_EXP_BLOCKS * S1_THREADS;
        for (; i < N_EDGES; i += stride)
            if (mask3[erow[i]]) mask2[ecol[i]] = 1;
    } else {
        int i = ((int)blockIdx.x - NBKT - S1_ACC_BLOCKS - S1_EXP_BLOCKS) * S1_THREADS
                + (int)threadIdx.x;
        if (i < N_NODES && mask3[i]) mask2[i] = 1;
    }
}

// ---------------------------------------------------------------------------
// spmm2 (layer 2): global ELL, masked, fp16 gathers + acc1 ride-along
// ---------------------------------------------------------------------------
__global__ void spmm_kernel(const int* __restrict__ counts,
                            const int2* __restrict__ ell,
                            const __half* __restrict__ xsrc,
                            const unsigned char* __restrict__ mask,
                            const int* __restrict__ ovf_cnt,
                            const int4* __restrict__ ovf,
                            const int* __restrict__ users,
                            const int* __restrict__ items,
                            float* __restrict__ acc_small,
                            __half* __restrict__ xout) {
    const int wid  = threadIdx.x >> 6;
    const int lane = threadIdx.x & 63;
    const int g    = lane >> 4;
    const int t    = lane & 15;

    if (blockIdx.x < SPMM_BLOCKS) {
        const int row = blockIdx.x * 16 + wid * 4 + g;
        bool active = mask[row] != 0;
        int cnt = 0;
        if (active) {
            cnt = counts[row];
            cnt = cnt < ELL_W ? cnt : ELL_W;
        }
        const int2* ep = ell + (size_t)row * ELL_W;
        float4 a0 = {0,0,0,0}, a1 = {0,0,0,0}, a2 = {0,0,0,0}, a3 = {0,0,0,0};
        int j = 0;
        for (; j + 4 <= cnt; j += 4) {
            int4 cv0 = *(const int4*)(ep + j);
            int4 cv1 = *(const int4*)(ep + j + 2);
            float4 x0 = loadh4(xsrc + (size_t)cv0.x * DIM + t * 4);
            float4 x1 = loadh4(xsrc + (size_t)cv0.z * DIM + t * 4);
            float4 x2 = loadh4(xsrc + (size_t)cv1.x * DIM + t * 4);
            float4 x3 = loadh4(xsrc + (size_t)cv1.z * DIM + t * 4);
            a0 = f4fma(__int_as_float(cv0.y), x0, a0);
            a1 = f4fma(__int_as_float(cv0.w), x1, a1);
            a2 = f4fma(__int_as_float(cv1.y), x2, a2);
            a3 = f4fma(__int_as_float(cv1.w), x3, a3);
        }
        for (; j + 2 <= cnt; j += 2) {
            int4 cv = *(const int4*)(ep + j);
            float4 x0 = loadh4(xsrc + (size_t)cv.x * DIM + t * 4);
            float4 x1 = loadh4(xsrc + (size_t)cv.z * DIM + t * 4);
            a0 = f4fma(__int_as_float(cv.y), x0, a0);
            a1 = f4fma(__int_as_float(cv.w), x1, a1);
        }
        if (j < cnt) {
            int2 cv = ep[j];
            float4 xv = loadh4(xsrc + (size_t)cv.x * DIM + t * 4);
            a0 = f4fma(__int_as_float(cv.y), xv, a0);
        }
        int novf = *ovf_cnt;
        if (novf > 0) {
            novf = novf < OVF_CAP ? novf : OVF_CAP;
            for (int k = 0; k < novf; ++k) {
                int4 o = ovf[k];
                if (active && o.x == row) {
                    float4 xv = loadh4(xsrc + (size_t)o.y * DIM + t * 4);
                    a0 = f4fma(__int_as_float(o.z), xv, a0);
                }
            }
        }
        if (active) {
            float4 self = loadh4(xsrc + (size_t)row * DIM + t * 4);
            float4 r;
            r.x = 0.2f * self.x + 0.8f * ((a0.x + a1.x) + (a2.x + a3.x));
            r.y = 0.2f * self.y + 0.8f * ((a0.y + a1.y) + (a2.y + a3.y));
            r.z = 0.2f * self.z + 0.8f * ((a0.z + a1.z) + (a2.z + a3.z));
            r.w = 0.2f * self.w + 0.8f * ((a0.w + a1.w) + (a2.w + a3.w));
            storeh4(xout + (size_t)row * DIM + t * 4, r);
        }
    } else {
        // acc1 += e1 at sampled slots (xsrc = emb_a)
        const int s = (blockIdx.x - SPMM_BLOCKS) * 16 + wid * 4 + g;
        const int node = (s < NB) ? users[s] : (NUM_USERS + items[s - NB]);
        float4 v = loadh4(xsrc + (size_t)node * DIM + t * 4);
        float4* ap = (float4*)(acc_small + (size_t)s * DIM + t * 4);
        float4 a = *ap;
        a.x += v.x; a.y += v.y; a.z += v.z; a.w += v.w;
        *ap = a;
    }
}

// ---------------------------------------------------------------------------
// sp3dot: slot-form layer 3 + fused batched dot.
//   Pair (user slot w, item slot NB+w) sit in adjacent 16-lane groups of the
//   same wave -> partner acc via shfl_xor(16), reduce via shfl_xor(1,2,4,8).
// ---------------------------------------------------------------------------
__global__ void sp3dot_kernel(const int* __restrict__ counts,
                              const int2* __restrict__ ell,
                              const __half* __restrict__ emb2,
                              const int* __restrict__ ovf_cnt,
                              const int4* __restrict__ ovf,
                              const int* __restrict__ users,
                              const int* __restrict__ items,
                              const float* __restrict__ acc_small,
                              float* __restrict__ out) {
    const int wid  = threadIdx.x >> 6;
    const int lane = threadIdx.x & 63;
    const int g    = lane >> 4;
    const int t    = lane & 15;
    const int G    = blockIdx.x * 16 + wid * 4 + g;       // < 8192
    if (G >= NSAMP) return;
    const int w    = G >> 1;
    const int role = G & 1;                    // 0 = user slot, 1 = item slot
    const int s    = role ? (NB + w) : w;
    const int node = role ? (NUM_USERS + items[w]) : users[w];

    int cnt = counts[node];
    cnt = cnt < ELL_W ? cnt : ELL_W;
    const int2* ep = ell + (size_t)node * ELL_W;
    float4 a0 = {0,0,0,0}, a1 = {0,0,0,0}, a2 = {0,0,0,0}, a3 = {0,0,0,0};
    int j = 0;
    for (; j + 4 <= cnt; j += 4) {
        int4 cv0 = *(const int4*)(ep + j);
        int4 cv1 = *(const int4*)(ep + j + 2);
        float4 x0 = loadh4(emb2 + (size_t)cv0.x * DIM + t * 4);
        float4 x1 = loadh4(emb2 + (size_t)cv0.z * DIM + t * 4);
        float4 x2 = loadh4(emb2 + (size_t)cv1.x * DIM + t * 4);
        float4 x3 = loadh4(emb2 + (size_t)cv1.z * DIM + t * 4);
        a0 = f4fma(__int_as_float(cv0.y), x0, a0);
        a1 = f4fma(__int_as_float(cv0.w), x1, a1);
        a2 = f4fma(__int_as_float(cv1.y), x2, a2);
        a3 = f4fma(__int_as_float(cv1.w), x3, a3);
    }
    for (; j + 2 <= cnt; j += 2) {
        int4 cv = *(const int4*)(ep + j);
        float4 x0 = loadh4(emb2 + (size_t)cv.x * DIM + t * 4);
        float4 x1 = loadh4(emb2 + (size_t)cv.z * DIM + t * 4);
        a0 = f4fma(__int_as_float(cv.y), x0, a0);
        a1 = f4fma(__int_as_float(cv.w), x1, a1);
    }
    if (j < cnt) {
        int2 cv = ep[j];
        float4 xv = loadh4(emb2 + (size_t)cv.x * DIM + t * 4);
        a0 = f4fma(__int_as_float(cv.y), xv, a0);
    }
    int novf = *ovf_cnt;
    if (novf > 0) {
        novf = novf < OVF_CAP ? novf : OVF_CAP;
        for (int k = 0; k < novf; ++k) {
            int4 o = ovf[k];
            if (o.x == node) {
                float4 xv = loadh4(emb2 + (size_t)o.y * DIM + t * 4);
                a0 = f4fma(__int_as_float(o.z), xv, a0);
            }
        }
    }
    float4 self = loadh4(emb2 + (size_t)node * DIM + t * 4);
    float4 a = *(const float4*)(acc_small + (size_t)s * DIM + t * 4);  // e0+e1
    a.x += 1.2f * self.x + 0.8f * ((a0.x + a1.x) + (a2.x + a3.x));
    a.y += 1.2f * self.y + 0.8f * ((a0.y + a1.y) + (a2.y + a3.y));
    a.z += 1.2f * self.z + 0.8f * ((a0.z + a1.z) + (a2.z + a3.z));
    a.w += 1.2f * self.w + 0.8f * ((a0.w + a1.w) + (a2.w + a3.w));
    // fused dot: partner group is lane^16 within the same wave
    float4 b;
    b.x = __shfl_xor(a.x, 16, 64);
    b.y = __shfl_xor(a.y, 16, 64);
    b.z = __shfl_xor(a.z, 16, 64);
    b.w = __shfl_xor(a.w, 16, 64);
    float p = a.x * b.x + a.y * b.y + a.z * b.z + a.w * b.w;
    p += __shfl_xor(p, 1, 64);
    p += __shfl_xor(p, 2, 64);
    p += __shfl_xor(p, 4, 64);
    p += __shfl_xor(p, 8, 64);
    if (role == 0 && t == 0) out[w] = p * 0.0625f;   // (u/4)·(i/4)
}

// ---------------------------------------------------------------------------
extern "C" void kernel_launch(void* const* d_in, const int* in_sizes, int n_in,
                              void* d_out, int out_size, void* d_ws, size_t ws_size,
                              hipStream_t stream) {
    const int*   users = (const int*)  d_in[0];
    const int*   items = (const int*)  d_in[1];
    const int*   erow  = (const int*)  d_in[2];
    const int*   ecol  = (const int*)  d_in[3];
    const float* evalv = (const float*)d_in[4];
    const float* ue    = (const float*)d_in[5];
    const float* ie    = (const float*)d_in[6];
    float* out = (float*)d_out;

    // workspace layout (~101 MB)
    __half* xh        = (__half*)d_ws;                      // 19.2 MB
    __half* emb_a     = xh + ND;                            // 19.2 MB
    __half* emb_b     = emb_a + ND;                         // 19.2 MB
    float*  acc_small = (float*)(emb_b + ND);               // 2 MB
    int2*   barr      = (int2*)(acc_small + NSAMP * DIM);   // 11.1 MB
    int2*   ell       = barr + (size_t)NBKT * BCAP;         // 28.9 MB
    int*    counts    = (int*)(ell + (size_t)NROWS_PAD * ELL_W); // 0.6 MB
    int*    gtails    = counts + NROWS_PAD;                 // NBKT
    int*    ovf_cnt   = gtails + NBKT;                      // 1
    int4*   ovf       = (int4*)(((uintptr_t)(ovf_cnt + 1) + 15) & ~(uintptr_t)15);
    unsigned char* mask3 = (unsigned char*)(ovf + OVF_CAP); // N_NODES
    unsigned char* mask2 = mask3 + N_NODES;                 // N_NODES

    // zero gtails | ovf_cnt | ovf | mask3 | mask2 (contiguous, ~310 KB)
    size_t zbytes = (size_t)((mask2 + N_NODES) - (unsigned char*)gtails);
    hipMemsetAsync(gtails, 0, zbytes, stream);

    k1_kernel<<<K1_EDGE_BLOCKS + K1_MARK_BLOCKS + K1_CVT_BLOCKS, K1_THREADS, 0, stream>>>(
        erow, ecol, evalv, users, items, ue, ie,
        gtails, barr, ovf, ovf_cnt, mask3, xh);

    // s1: ELL build + pruned writeout + layer-1 spmm + acc0 + expand + copy
    s1_kernel<<<NBKT + S1_ACC_BLOCKS + S1_EXP_BLOCKS + S1_CPY_BLOCKS, S1_THREADS, 0, stream>>>(
        erow, ecol, gtails, barr, xh, ue, ie, counts, ell, ovf, ovf_cnt,
        mask3, mask2, users, items, acc_small, emb_a);

    // layer 2 (mask2) + acc1 (from emb_a)
    spmm_kernel<<<SPMM_BLOCKS + ACC_BLOCKS, 256, 0, stream>>>(
        counts, ell, emb_a, mask2, ovf_cnt, ovf,
        users, items, acc_small, emb_b);

    // layer 3 slot-form + fused dot
    sp3dot_kernel<<<SP3_BLOCKS, 256, 0, stream>>>(
        counts, ell, emb_b, ovf_cnt, ovf, users, items, acc_small, out);
}